// Round 4
// baseline (56.619 us; speedup 1.0000x reference)
//
#include <hip/hip_runtime.h>
#include <hip/hip_bf16.h>

// Problem constants
#define PM 8        // groups
#define PK 4096     // codebook entries per group
#define PD 128      // dim
#define PN 8
#define PH 64
#define PW 64

typedef __attribute__((ext_vector_type(8))) short bf16x8;
typedef __attribute__((ext_vector_type(4))) float f32x4;
typedef __attribute__((ext_vector_type(8))) short short8v;

__device__ inline unsigned short f2bf_rne(float f) {
    unsigned int u = __float_as_uint(f);
    unsigned int r = (u + 0x7FFFu + ((u >> 16) & 1u)) >> 16;
    return (unsigned short)r;
}
__device__ inline float bf2f(unsigned short s) {
    return __uint_as_float(((unsigned int)s) << 16);
}

__device__ inline bf16x8 loadcvt8(const float* __restrict__ p) {
    f32x4 x0 = *(const f32x4*)p;
    f32x4 x1 = *(const f32x4*)(p + 4);
    bf16x8 r;
#pragma unroll
    for (int j = 0; j < 4; ++j) {
        r[j]     = (short)f2bf_rne(x0[j]);
        r[j + 4] = (short)f2bf_rne(x1[j]);
    }
    return r;
}

// ---------------------------------------------------------------------------
// Kernel 1: EXACT round-1 build_table (256 blocks). Do not touch — this
// round's probe subtraction requires k1+k2 == round-1's 41.8 us baseline.
// ---------------------------------------------------------------------------
__global__ __launch_bounds__(256) void build_table(
        const float* __restrict__ codebook,
        const float* __restrict__ wq,
        const float* __restrict__ bq,
        unsigned short* __restrict__ table) {
    const int b = blockIdx.x;
    const int m = b & 7;
    const int ktile = (b >> 3) * 128;
    const int tid = threadIdx.x;
    const int wv = tid >> 6;       // wave 0..3
    const int l  = tid & 63;
    const int lr = l & 15;         // frag row/col index
    const int lg = l >> 4;         // k-chunk group 0..3

    const float* cb = codebook + (size_t)m * PK * PD;
    const float* wm = wq + (size_t)m * PD * PD;

    bf16x8 afrag[2][4];
#pragma unroll
    for (int ks = 0; ks < 2; ++ks) {
        const int k = ktile + wv * 32 + ks * 16 + lr;
        const float* src = cb + (size_t)k * PD + lg * 8;
#pragma unroll
        for (int kk = 0; kk < 4; ++kk) {
            afrag[ks][kk] = loadcvt8(src + kk * 32);
        }
    }

#pragma unroll
    for (int cs = 0; cs < 8; ++cs) {
        const int c = cs * 16 + lr;
        bf16x8 bfrag[4];
        const float* src = wm + (size_t)c * PD + lg * 8;
#pragma unroll
        for (int kk = 0; kk < 4; ++kk) {
            bfrag[kk] = loadcvt8(src + kk * 32);
        }
        const float bias = bq[m * PD + c];
#pragma unroll
        for (int ks = 0; ks < 2; ++ks) {
            f32x4 acc = {0.f, 0.f, 0.f, 0.f};
#pragma unroll
            for (int kk = 0; kk < 4; ++kk) {
                acc = __builtin_amdgcn_mfma_f32_16x16x32_bf16(
                        afrag[ks][kk], bfrag[kk], acc, 0, 0, 0);
            }
            // C/D layout: col = lane&15, row = (lane>>4)*4 + j   [m89 verified]
            const int kb = ktile + wv * 32 + ks * 16 + lg * 4;
            unsigned short* dst = table + ((size_t)(m * PK + kb)) * PD + cs * 16 + lr;
#pragma unroll
            for (int j = 0; j < 4; ++j) {
                dst[(size_t)j * PD] = f2bf_rne(acc[j] + bias);
            }
        }
    }
}

// ---------------------------------------------------------------------------
// PROBE: k2's exact read path (code load -> 4x16B table gathers), stores
// removed, values kept live via asm sinks (prevents DCE of the gathers).
// Writes nothing; inserted into the timed graph purely to measure the
// read-path cost: g = total - 41.8us (round-1 k1+k2 baseline).
// ---------------------------------------------------------------------------
__global__ __launch_bounds__(256) void gather_probe(
        const int* __restrict__ codes,
        const unsigned short* __restrict__ table) {
    const int b = blockIdx.x;
    const int m = b & 7;
    const int rest = b >> 3;
    const int n = rest >> 6;
    const int h = rest & 63;
    const int tid = threadIdx.x;
    const int w = tid & 63;
    const int cb0 = (tid >> 6) * 32;

    const int code = codes[((n * PH + h) * PW + w) * PM + m];
    const unsigned short* row = table + ((size_t)m * PK + code) * PD + cb0;

#pragma unroll
    for (int i = 0; i < 4; ++i) {
        short8v v = *(const short8v*)(row + i * 8);
        f32x4 vv = *(f32x4*)&v;
        asm volatile("" :: "v"(vv));   // keep full 16B gather live
    }
}

// ---------------------------------------------------------------------------
// Kernel 2: EXACT round-1 gather_scatter (4096 blocks, scalar NT stores).
// ---------------------------------------------------------------------------
__global__ __launch_bounds__(256) void gather_scatter(
        const int* __restrict__ codes,
        const unsigned short* __restrict__ table,
        float* __restrict__ out) {
    const int b = blockIdx.x;
    const int m = b & 7;
    const int rest = b >> 3;
    const int n = rest >> 6;
    const int h = rest & 63;
    const int tid = threadIdx.x;
    const int w = tid & 63;
    const int cb0 = (tid >> 6) * 32;   // 0,32,64,96 per wave

    const int code = codes[((n * PH + h) * PW + w) * PM + m];
    const unsigned short* row = table + ((size_t)m * PK + code) * PD + cb0;
    float* ob = out + (((size_t)n * (PM * PD) + m * PD + cb0) * PH + h) * PW + w;

#pragma unroll
    for (int i = 0; i < 4; ++i) {
        short8v v = *(const short8v*)(row + i * 8);
#pragma unroll
        for (int j = 0; j < 8; ++j) {
            __builtin_nontemporal_store(bf2f((unsigned short)v[j]),
                                        ob + (size_t)(i * 8 + j) * (PH * PW));
        }
    }
}

// ---------------------------------------------------------------------------
// Fallback (only if ws_size < table size): fused direct compute, fp32.
// ---------------------------------------------------------------------------
__global__ __launch_bounds__(256) void fused_direct(
        const int* __restrict__ codes,
        const float* __restrict__ codebook,
        const float* __restrict__ wq,
        const float* __restrict__ bq,
        float* __restrict__ out) {
    __shared__ float rows[PW][133];
    const int b = blockIdx.x;
    const int m = b & 7;
    const int rest = b >> 3;
    const int n = rest >> 6;
    const int h = rest & 63;
    const int tid = threadIdx.x;

    for (int idx = tid; idx < PW * 32; idx += 256) {
        const int r = idx >> 5;
        const int e = (idx & 31) * 4;
        const int code = codes[((n * PH + h) * PW + r) * PM + m];
        const float* src = codebook + ((size_t)m * PK + code) * PD + e;
#pragma unroll
        for (int j = 0; j < 4; ++j) rows[r][e + j] = src[j];
    }
    __syncthreads();

    const int w = tid & 63;
    const int cb0 = (tid >> 6) * 32;
    float* ob = out + (((size_t)n * (PM * PD) + m * PD + cb0) * PH + h) * PW + w;
    for (int ci = 0; ci < 32; ++ci) {
        const int c = cb0 + ci;
        const float* wr = wq + ((size_t)m * PD + c) * PD;
        float acc = bq[m * PD + c];
#pragma unroll 4
        for (int d = 0; d < PD; ++d) acc += rows[w][d] * wr[d];
        ob[(size_t)ci * (PH * PW)] = acc;
    }
}

extern "C" void kernel_launch(void* const* d_in, const int* in_sizes, int n_in,
                              void* d_out, int out_size, void* d_ws, size_t ws_size,
                              hipStream_t stream) {
    const int*   codes    = (const int*)  d_in[0];
    const float* codebook = (const float*)d_in[1];
    const float* wq       = (const float*)d_in[2];
    const float* bq       = (const float*)d_in[3];
    float* out = (float*)d_out;

    const size_t table_bytes = (size_t)PM * PK * PD * sizeof(unsigned short); // 8 MB
    if (ws_size >= table_bytes) {
        unsigned short* table = (unsigned short*)d_ws;
        build_table<<<dim3(256), dim3(256), 0, stream>>>(codebook, wq, bq, table);
        gather_probe<<<dim3(PM * PN * PH), dim3(256), 0, stream>>>(codes, table);
        gather_scatter<<<dim3(PM * PN * PH), dim3(256), 0, stream>>>(codes, table, out);
    } else {
        fused_direct<<<dim3(PM * PN * PH), dim3(256), 0, stream>>>(codes, codebook, wq, bq, out);
    }
}

// Round 5
// 37.581 us; speedup vs baseline: 1.5066x; 1.5066x over previous
//
#include <hip/hip_runtime.h>
#include <hip/hip_bf16.h>

// Problem constants
#define PM 8        // groups
#define PK 4096     // codebook entries per group
#define PD 128      // dim
#define PN 8
#define PH 64
#define PW 64

typedef __attribute__((ext_vector_type(8))) short bf16x8;
typedef __attribute__((ext_vector_type(4))) float f32x4;
typedef __attribute__((ext_vector_type(8))) short short8v;

__device__ inline unsigned short f2bf_rne(float f) {
    unsigned int u = __float_as_uint(f);
    unsigned int r = (u + 0x7FFFu + ((u >> 16) & 1u)) >> 16;
    return (unsigned short)r;
}
__device__ inline float bf2f(unsigned short s) {
    return __uint_as_float(((unsigned int)s) << 16);
}

__device__ inline bf16x8 loadcvt8(const float* __restrict__ p) {
    f32x4 x0 = *(const f32x4*)p;
    f32x4 x1 = *(const f32x4*)(p + 4);
    bf16x8 r;
#pragma unroll
    for (int j = 0; j < 4; ++j) {
        r[j]     = (short)f2bf_rne(x0[j]);
        r[j + 4] = (short)f2bf_rne(x1[j]);
    }
    return r;
}

// ---------------------------------------------------------------------------
// Kernel 1 v3: table[m,k,c] = sum_d codebook[m,k,d]*wq[m,c,d] + bq[m,c] (bf16)
// Changes vs R1:
//  - wq[m] staged ONCE per block into LDS as frag-major bf16 (32 KB): unit
//    u=(cs,kk,lg), slot lr. Both ds_write and ds_read are contiguous-1KB
//    per instruction -> bank-optimal. Kills the 64 MB redundant wq re-read.
//  - MFMA operands SWAPPED: mfma(wq_frag, cb_frag) -> D[row=c][col=k]
//    (dot products identical; m89 layout: col=lane&15 -> k, row=lg*4+j -> c).
//    Lane then holds 4 CONSECUTIVE c values -> one packed 8 B store per tile
//    (16 stores/thread of 8 B vs R1's 64 scalar 2 B stores).
//  - bq staged in LDS, read as broadcast f32x4.
// Grid: 256 blocks (m = b&7, kt0 = (b>>3)*128), 256 threads = 4 waves,
// wave = 32 k-rows (2 x 16-row subtiles).
// ---------------------------------------------------------------------------
__global__ __launch_bounds__(256) void build_table(
        const float* __restrict__ codebook,
        const float* __restrict__ wq,
        const float* __restrict__ bq,
        unsigned short* __restrict__ table) {
    __shared__ unsigned short ldsA[2048 * 8];   // 2048 frag-units x 16 B = 32 KB
    __shared__ float lds_bq[PD];
    const int b = blockIdx.x;
    const int m = b & 7;
    const int kt0 = (b >> 3) * 128;
    const int tid = threadIdx.x;
    const int wv = tid >> 6;
    const int l  = tid & 63;
    const int lr = l & 15;
    const int lg = l >> 4;

    const float* cb = codebook + (size_t)m * PK * PD;
    const float* wm = wq + (size_t)m * PD * PD;

    if (tid < PD) lds_bq[tid] = bq[m * PD + tid];

    // Stage wq -> LDS frag-major: unit u = (cs<<4)|(kk<<2)|lg holds
    // wq[cs*16 + slot][kk*32 + lg*8 .. +8) as bf16x8 at slot index.
    {
        const int lr_s = tid & 15;
        const int u0 = (tid >> 4) * 8;
#pragma unroll
        for (int i = 0; i < 8; ++i) {
            const int u  = u0 + i;
            const int cs = u >> 4;
            const int kk = (u >> 2) & 3;
            const int lgs = u & 3;
            bf16x8 v = loadcvt8(wm + (size_t)(cs * 16 + lr_s) * PD + kk * 32 + lgs * 8);
            *(bf16x8*)&ldsA[(size_t)(u * 16 + lr_s) * 8] = v;
        }
    }

    // Codebook B-frags (per-wave k rows), loaded while staging is in flight.
    bf16x8 bfragc[2][4];
#pragma unroll
    for (int ks = 0; ks < 2; ++ks) {
        const int k = kt0 + wv * 32 + ks * 16 + lr;
        const float* src = cb + (size_t)k * PD + lg * 8;
#pragma unroll
        for (int kk = 0; kk < 4; ++kk) {
            bfragc[ks][kk] = loadcvt8(src + kk * 32);
        }
    }
    __syncthreads();

#pragma unroll
    for (int cs = 0; cs < 8; ++cs) {
        bf16x8 afragw[4];
#pragma unroll
        for (int kk = 0; kk < 4; ++kk) {
            const int u = (cs << 4) | (kk << 2) | lg;
            afragw[kk] = *(const bf16x8*)&ldsA[(size_t)(u * 16 + lr) * 8];
        }
        const f32x4 bias4 = *(const f32x4*)&lds_bq[cs * 16 + lg * 4];
#pragma unroll
        for (int ks = 0; ks < 2; ++ks) {
            f32x4 acc = {0.f, 0.f, 0.f, 0.f};
#pragma unroll
            for (int kk = 0; kk < 4; ++kk) {
                acc = __builtin_amdgcn_mfma_f32_16x16x32_bf16(
                        afragw[kk], bfragc[ks][kk], acc, 0, 0, 0);
            }
            // D[row = c = cs*16 + lg*4 + j][col = k = kt0+wv*32+ks*16+lr]
            const int k = kt0 + wv * 32 + ks * 16 + lr;
            unsigned int p0 = (unsigned int)f2bf_rne(acc[0] + bias4[0])
                            | ((unsigned int)f2bf_rne(acc[1] + bias4[1]) << 16);
            unsigned int p1 = (unsigned int)f2bf_rne(acc[2] + bias4[2])
                            | ((unsigned int)f2bf_rne(acc[3] + bias4[3]) << 16);
            uint2 pk; pk.x = p0; pk.y = p1;
            *(uint2*)&table[((size_t)(m * PK + k)) * PD + cs * 16 + lg * 4] = pk;
        }
    }
}

// ---------------------------------------------------------------------------
// Kernel 2 v4: EXACT round-1 gather_scatter, with ONE change: plain stores
// instead of __builtin_nontemporal_store (A/B test: NT bypasses L2 write
// aggregation; the 6.8 TB/s fill kernel uses regular stores).
// ---------------------------------------------------------------------------
__global__ __launch_bounds__(256) void gather_scatter(
        const int* __restrict__ codes,
        const unsigned short* __restrict__ table,
        float* __restrict__ out) {
    const int b = blockIdx.x;
    const int m = b & 7;
    const int rest = b >> 3;
    const int n = rest >> 6;
    const int h = rest & 63;
    const int tid = threadIdx.x;
    const int w = tid & 63;
    const int cb0 = (tid >> 6) * 32;   // 0,32,64,96 per wave

    const int code = codes[((n * PH + h) * PW + w) * PM + m];
    const unsigned short* row = table + ((size_t)m * PK + code) * PD + cb0;
    float* ob = out + (((size_t)n * (PM * PD) + m * PD + cb0) * PH + h) * PW + w;

#pragma unroll
    for (int i = 0; i < 4; ++i) {
        short8v v = *(const short8v*)(row + i * 8);
#pragma unroll
        for (int j = 0; j < 8; ++j) {
            ob[(size_t)(i * 8 + j) * (PH * PW)] = bf2f((unsigned short)v[j]);
        }
    }
}

// ---------------------------------------------------------------------------
// Fallback (only if ws_size < table size): fused direct compute, fp32.
// ---------------------------------------------------------------------------
__global__ __launch_bounds__(256) void fused_direct(
        const int* __restrict__ codes,
        const float* __restrict__ codebook,
        const float* __restrict__ wq,
        const float* __restrict__ bq,
        float* __restrict__ out) {
    __shared__ float rows[PW][133];
    const int b = blockIdx.x;
    const int m = b & 7;
    const int rest = b >> 3;
    const int n = rest >> 6;
    const int h = rest & 63;
    const int tid = threadIdx.x;

    for (int idx = tid; idx < PW * 32; idx += 256) {
        const int r = idx >> 5;
        const int e = (idx & 31) * 4;
        const int code = codes[((n * PH + h) * PW + r) * PM + m];
        const float* src = codebook + ((size_t)m * PK + code) * PD + e;
#pragma unroll
        for (int j = 0; j < 4; ++j) rows[r][e + j] = src[j];
    }
    __syncthreads();

    const int w = tid & 63;
    const int cb0 = (tid >> 6) * 32;
    float* ob = out + (((size_t)n * (PM * PD) + m * PD + cb0) * PH + h) * PW + w;
    for (int ci = 0; ci < 32; ++ci) {
        const int c = cb0 + ci;
        const float* wr = wq + ((size_t)m * PD + c) * PD;
        float acc = bq[m * PD + c];
#pragma unroll 4
        for (int d = 0; d < PD; ++d) acc += rows[w][d] * wr[d];
        ob[(size_t)ci * (PH * PW)] = acc;
    }
}

extern "C" void kernel_launch(void* const* d_in, const int* in_sizes, int n_in,
                              void* d_out, int out_size, void* d_ws, size_t ws_size,
                              hipStream_t stream) {
    const int*   codes    = (const int*)  d_in[0];
    const float* codebook = (const float*)d_in[1];
    const float* wq       = (const float*)d_in[2];
    const float* bq       = (const float*)d_in[3];
    float* out = (float*)d_out;

    const size_t table_bytes = (size_t)PM * PK * PD * sizeof(unsigned short); // 8 MB
    if (ws_size >= table_bytes) {
        unsigned short* table = (unsigned short*)d_ws;
        build_table<<<dim3(256), dim3(256), 0, stream>>>(codebook, wq, bq, table);
        gather_scatter<<<dim3(PM * PN * PH), dim3(256), 0, stream>>>(codes, table, out);
    } else {
        fused_direct<<<dim3(PM * PN * PH), dim3(256), 0, stream>>>(codes, codebook, wq, bq, out);
    }
}